// Round 2
// baseline (155.141 us; speedup 1.0000x reference)
//
#include <hip/hip_runtime.h>

// Trilinear interp of [64,64,64,64] fp32 volume at 200k random points.
// R2: spatial counting-sort of points (Morton 32^3 bins of 2^3 voxels) so
// consecutive waves gather from overlapping voxel footprints -> L2 locality.
// Passes: memset bins -> histogram -> scan -> scatter(sorted coords+idx) -> gather.

#define NBINS 32768          // 32^3
#define SCAN_THREADS 1024
#define BINS_PER_THREAD 32   // 1024*32 = 32768

__device__ __forceinline__ float4 f4mul(float4 a, float s) {
    return make_float4(a.x * s, a.y * s, a.z * s, a.w * s);
}
__device__ __forceinline__ float4 f4fma(float4 a, float s, float4 acc) {
    return make_float4(fmaf(a.x, s, acc.x), fmaf(a.y, s, acc.y),
                       fmaf(a.z, s, acc.z), fmaf(a.w, s, acc.w));
}

__device__ __forceinline__ unsigned part1by2(unsigned x) {
    x &= 0x3FF;
    x = (x | (x << 16)) & 0x030000FF;
    x = (x | (x << 8))  & 0x0300F00F;
    x = (x | (x << 4))  & 0x030C30C3;
    x = (x | (x << 2))  & 0x09249249;
    return x;
}

__device__ __forceinline__ int bin_of(float xs, float ys, float zs) {
    // xs,ys,zs already scaled to [0,64)
    unsigned bx = ((unsigned)(int)floorf(xs)) >> 1;   // 0..31
    unsigned by = ((unsigned)(int)floorf(ys)) >> 1;
    unsigned bz = ((unsigned)(int)floorf(zs)) >> 1;
    return (int)(part1by2(bx) | (part1by2(by) << 1) | (part1by2(bz) << 2));
}

__global__ __launch_bounds__(256) void hist_kernel(
    const float* __restrict__ coords, int* __restrict__ bins, int n)
{
    int p = blockIdx.x * 256 + threadIdx.x;
    if (p >= n) return;
    float xs = coords[3 * p + 0] * 0.5f;
    float ys = coords[3 * p + 1] * 0.5f;
    float zs = coords[3 * p + 2] * 0.5f;
    atomicAdd(&bins[bin_of(xs, ys, zs)], 1);
}

__global__ __launch_bounds__(SCAN_THREADS) void scan_kernel(int* __restrict__ bins)
{
    __shared__ int sums[SCAN_THREADS];
    int t = threadIdx.x;
    int base = t * BINS_PER_THREAD;
    int local[BINS_PER_THREAD];
    int s = 0;
    #pragma unroll
    for (int i = 0; i < BINS_PER_THREAD; i++) local[i] = bins[base + i];
    #pragma unroll
    for (int i = 0; i < BINS_PER_THREAD; i++) { int v = local[i]; local[i] = s; s += v; }
    sums[t] = s;
    __syncthreads();
    // Hillis-Steele inclusive scan over 1024 partials
    for (int off = 1; off < SCAN_THREADS; off <<= 1) {
        int v = (t >= off) ? sums[t - off] : 0;
        __syncthreads();
        sums[t] += v;
        __syncthreads();
    }
    int prefix = (t == 0) ? 0 : sums[t - 1];
    #pragma unroll
    for (int i = 0; i < BINS_PER_THREAD; i++) bins[base + i] = local[i] + prefix;
}

__global__ __launch_bounds__(256) void scatter_kernel(
    const float* __restrict__ coords, int* __restrict__ offs,
    float4* __restrict__ coordsS, int n)
{
    int p = blockIdx.x * 256 + threadIdx.x;
    if (p >= n) return;
    float xs = coords[3 * p + 0] * 0.5f;
    float ys = coords[3 * p + 1] * 0.5f;
    float zs = coords[3 * p + 2] * 0.5f;
    int r = atomicAdd(&offs[bin_of(xs, ys, zs)], 1);
    coordsS[r] = make_float4(xs, ys, zs, __int_as_float(p));
}

__global__ __launch_bounds__(256) void trilerp_sorted_kernel(
    const float* __restrict__ img, const float4* __restrict__ coordsS,
    float* __restrict__ out, int n_points, int per_xcd)
{
    // XCD chunk swizzle: blocks dispatched round-robin over 8 XCDs; give each
    // XCD a contiguous range of the sorted order for L2 locality.
    // gridDim.x is padded to a multiple of 8, per_xcd = gridDim.x/8 -> bijection.
    int b = (blockIdx.x & 7) * per_xcd + (blockIdx.x >> 3);
    int tid = b * 256 + threadIdx.x;
    int sp = tid >> 4;             // sorted point position
    if (sp >= n_points) return;
    int cvec = tid & 15;

    float4 cs = coordsS[sp];
    float x = cs.x, y = cs.y, z = cs.z;
    int p = __float_as_int(cs.w);  // original point index

    float fx1 = floorf(x), fx2 = fminf(ceilf(x), 63.0f);
    float fy1 = floorf(y), fy2 = fminf(ceilf(y), 63.0f);
    float fz1 = floorf(z), fz2 = fminf(ceilf(z), 63.0f);

    float wx = x - fx1, wxc = fx2 - x;
    float wy = y - fy1, wyc = fy2 - y;
    float wz = z - fz1, wzc = fz2 - z;

    int ix1 = (int)fx1, ix2 = (int)fx2;
    int iy1 = (int)fy1, iy2 = (int)fy2;
    int iz1 = (int)fz1, iz2 = (int)fz2;

    const float4* __restrict__ imgv = (const float4*)img;
    int bx1 = ix1 << 12, bx2 = ix2 << 12;
    int by1 = iy1 << 6,  by2 = iy2 << 6;

    float4 q11 = imgv[((bx1 + by1 + iz1) << 4) + cvec];
    float4 q21 = imgv[((bx2 + by1 + iz1) << 4) + cvec];
    float4 q12 = imgv[((bx1 + by2 + iz1) << 4) + cvec];
    float4 q22 = imgv[((bx2 + by2 + iz1) << 4) + cvec];
    float4 ly1 = f4fma(f4fma(q22, wx, f4mul(q12, wxc)), wy,
                       f4mul(f4fma(q21, wx, f4mul(q11, wxc)), wyc));

    q11 = imgv[((bx1 + by1 + iz2) << 4) + cvec];
    q21 = imgv[((bx2 + by1 + iz2) << 4) + cvec];
    q12 = imgv[((bx1 + by2 + iz2) << 4) + cvec];
    q22 = imgv[((bx2 + by2 + iz2) << 4) + cvec];
    float4 ly2 = f4fma(f4fma(q22, wx, f4mul(q12, wxc)), wy,
                       f4mul(f4fma(q21, wx, f4mul(q11, wxc)), wyc));

    float4 res = f4fma(ly2, wz, f4mul(ly1, wzc));
    ((float4*)out)[(p << 4) + cvec] = res;
}

// Fallback (R1 kernel) if workspace is too small for the sort.
__global__ __launch_bounds__(256) void trilerp_kernel(
    const float* __restrict__ img, const float* __restrict__ coords,
    float* __restrict__ out, int n_points)
{
    int tid = blockIdx.x * 256 + threadIdx.x;
    int p = tid >> 4;
    if (p >= n_points) return;
    int cvec = tid & 15;

    float x = coords[3 * p + 0] * 0.5f;
    float y = coords[3 * p + 1] * 0.5f;
    float z = coords[3 * p + 2] * 0.5f;

    float fx1 = floorf(x), fx2 = fminf(ceilf(x), 63.0f);
    float fy1 = floorf(y), fy2 = fminf(ceilf(y), 63.0f);
    float fz1 = floorf(z), fz2 = fminf(ceilf(z), 63.0f);

    float wx = x - fx1, wxc = fx2 - x;
    float wy = y - fy1, wyc = fy2 - y;
    float wz = z - fz1, wzc = fz2 - z;

    int ix1 = (int)fx1, ix2 = (int)fx2;
    int iy1 = (int)fy1, iy2 = (int)fy2;
    int iz1 = (int)fz1, iz2 = (int)fz2;

    const float4* __restrict__ imgv = (const float4*)img;
    int bx1 = ix1 << 12, bx2 = ix2 << 12;
    int by1 = iy1 << 6,  by2 = iy2 << 6;

    float4 q11 = imgv[((bx1 + by1 + iz1) << 4) + cvec];
    float4 q21 = imgv[((bx2 + by1 + iz1) << 4) + cvec];
    float4 q12 = imgv[((bx1 + by2 + iz1) << 4) + cvec];
    float4 q22 = imgv[((bx2 + by2 + iz1) << 4) + cvec];
    float4 ly1 = f4fma(f4fma(q22, wx, f4mul(q12, wxc)), wy,
                       f4mul(f4fma(q21, wx, f4mul(q11, wxc)), wyc));

    q11 = imgv[((bx1 + by1 + iz2) << 4) + cvec];
    q21 = imgv[((bx2 + by1 + iz2) << 4) + cvec];
    q12 = imgv[((bx1 + by2 + iz2) << 4) + cvec];
    q22 = imgv[((bx2 + by2 + iz2) << 4) + cvec];
    float4 ly2 = f4fma(f4fma(q22, wx, f4mul(q12, wxc)), wy,
                       f4mul(f4fma(q21, wx, f4mul(q11, wxc)), wyc));

    float4 res = f4fma(ly2, wz, f4mul(ly1, wzc));
    ((float4*)out)[(p << 4) + cvec] = res;
}

extern "C" void kernel_launch(void* const* d_in, const int* in_sizes, int n_in,
                              void* d_out, int out_size, void* d_ws, size_t ws_size,
                              hipStream_t stream) {
    const float* img    = (const float*)d_in[0];   // [1,64,64,64,64]
    const float* coords = (const float*)d_in[1];   // [1,N,3]
    float* out = (float*)d_out;                    // [1,N,64]
    int n = in_sizes[1] / 3;

    size_t bins_bytes   = (size_t)NBINS * sizeof(int);
    size_t coordsS_off  = bins_bytes;                       // 131072, 16B-aligned
    size_t need = coordsS_off + (size_t)n * sizeof(float4);

    if (ws_size >= need) {
        int* bins       = (int*)d_ws;
        float4* coordsS = (float4*)((char*)d_ws + coordsS_off);

        hipMemsetAsync(bins, 0, bins_bytes, stream);

        int pgrid = (n + 255) / 256;
        hist_kernel<<<pgrid, 256, 0, stream>>>(coords, bins, n);
        scan_kernel<<<1, SCAN_THREADS, 0, stream>>>(bins);
        scatter_kernel<<<pgrid, 256, 0, stream>>>(coords, bins, coordsS, n);

        int threads = n * 16;
        int nb = (threads + 255) / 256;
        int nb_pad = (nb + 7) & ~7;          // multiple of 8 for bijective swizzle
        int per_xcd = nb_pad >> 3;
        trilerp_sorted_kernel<<<nb_pad, 256, 0, stream>>>(img, coordsS, out, n, per_xcd);
    } else {
        int threads = n * 16;
        int grid = (threads + 255) / 256;
        trilerp_kernel<<<grid, 256, 0, stream>>>(img, coords, out, n);
    }
}